// Round 3
// baseline (339.481 us; speedup 1.0000x reference)
//
#include <hip/hip_runtime.h>

typedef unsigned short u16;
typedef __bf16 bf16x8 __attribute__((ext_vector_type(8)));
typedef float f32x4 __attribute__((ext_vector_type(4)));

#define WEMD 400
#define RANK 396
#define NA   16384     // SEQ*BATCH
#define KP   416       // padded wemd (400->416) for gemm_h K
#define K2   448       // padded rank (396->448) for gemm_big K (7 tiles of 64)
#define BSTR 896       // byte stride of H and G rows (448*2)
#define NBC  2500
#define NBCP 2560

// ---- ws layout (bytes) ----
#define OFF_WBF  0u                 // u16 [16416][416]
#define OFF_UBT  13658112u          // u16 [512][416]
#define OFF_TBT  14084096u          // u16 [512][416]
#define OFF_G    14689280u          // u16 [2560][448]
#define OFF_H    16983040u          // u16 [16384][448]   total ~31.7 MB

__device__ __forceinline__ u16 f2bf(float f) {
  union { float f; unsigned u; } v; v.f = f;
  unsigned u = v.u;
  return (u16)((u + 0x7FFFu + ((u >> 16) & 1u)) >> 16);  // RNE
}

typedef __attribute__((address_space(3))) unsigned char lds_byte;
typedef __attribute__((address_space(1))) const unsigned char glob_byte;

__device__ __forceinline__ void gload16(const void* g, void* l) {
  __builtin_amdgcn_global_load_lds((glob_byte*)g, (lds_byte*)l, 16, 0, 0);
}

#define FENCE() asm volatile("" ::: "memory")
#define BARRIER() do { FENCE(); __builtin_amdgcn_s_barrier(); FENCE(); } while (0)
#define VMCNT4() asm volatile("s_waitcnt vmcnt(4)" ::: "memory")

// ---------- fused prep: Wbf + Ubt/Tbt + G in one grid-stride kernel ----------
__global__ __launch_bounds__(256) void prep_all(
    const float* __restrict__ word, const float* __restrict__ first,
    const float* __restrict__ U, const float* __restrict__ T,
    const float* __restrict__ tag, const float* __restrict__ V,
    const float* __restrict__ W,
    u16* __restrict__ Wbf, u16* __restrict__ Ubt, u16* __restrict__ Tbt,
    u16* __restrict__ G) {
  const int R0 = 16416 * 104;          // Wbf as float4 items (416/4 = 104 per row)
  const int R1 = 416 << 9;             // U/T transpose: k = j>>9 (0..415), n = j&511
  const int R2 = NBCP * K2;            // G items
  const int total = R0 + R1 + R2;
  for (int i = blockIdx.x * 256 + threadIdx.x; i < total; i += gridDim.x * 256) {
    if (i < R0) {
      int r = i / 104, c4 = i - r * 104;
      ushort4 o = {0, 0, 0, 0};
      if (c4 < 100) {
        const float* src = (r < 32) ? (first + c4 * 4)
                                    : (word + (size_t)(r - 32) * WEMD + c4 * 4);
        float4 v = *(const float4*)src;
        o.x = f2bf(v.x); o.y = f2bf(v.y); o.z = f2bf(v.z); o.w = f2bf(v.w);
      }
      *(ushort4*)(Wbf + (size_t)r * KP + c4 * 4) = o;
    } else if (i < R0 + R1) {
      int j = i - R0;
      int n = j & 511, k = j >> 9;
      u16 uo = 0, to = 0;
      if (n < RANK && k < WEMD) {
        uo = f2bf(U[(size_t)k * RANK + n]);
        to = f2bf(T[(size_t)k * RANK + n]);
      }
      Ubt[(size_t)n * KP + k] = uo;
      Tbt[(size_t)n * KP + k] = to;
    } else {
      int j = i - R0 - R1;
      int bc = j / K2, k = j - bc * K2;
      u16 g = 0;
      if (bc < NBC && k < RANK) {
        int b = bc / 50, c = bc - b * 50;
        float a2 = 0.f, a3 = 0.f;
        #pragma unroll
        for (int e = 0; e < 20; ++e) {
          a2 += tag[b * 20 + e] * V[e * RANK + k];
          a3 += tag[c * 20 + e] * W[e * RANK + k];
        }
        g = f2bf(a2 * a3);
      }
      G[(size_t)bc * K2 + k] = g;
    }
  }
}

// ---------- H = (word@U) * (neighbor@T), bf16 out, stride 448 ----------
__global__ __launch_bounds__(256) void gemm_h(const u16* __restrict__ Wbf,
                                              const u16* __restrict__ Ubt,
                                              const u16* __restrict__ Tbt,
                                              u16* __restrict__ H) {
  __shared__ u16 As0[128 * 32], As1[128 * 32], Bu[128 * 32], Bt[128 * 32];
  const int tid = threadIdx.x;
  const int l = tid & 63, w = tid >> 6;
  const int wm = w >> 1, wn = w & 1;
  const int tm = (blockIdx.x >> 2) * 128, tn = (blockIdx.x & 3) * 128;

  f32x4 acc0[4][4] = {}, acc1[4][4] = {};

  const int srow = tid >> 2;
  const int scolb = (tid & 3) * 16;
  const char* gA0 = (const char*)Wbf + (size_t)(tm + 32 + srow) * 832 + scolb;
  const char* gA1 = (const char*)Wbf + (size_t)(tm + srow) * 832 + scolb;
  const char* gU  = (const char*)Ubt + (size_t)(tn + srow) * 832 + scolb;
  const char* gT  = (const char*)Tbt + (size_t)(tn + srow) * 832 + scolb;
  char* lA0 = (char*)As0 + tid * 16;
  char* lA1 = (char*)As1 + tid * 16;
  char* lU  = (char*)Bu  + tid * 16;
  char* lT  = (char*)Bt  + tid * 16;

  const int fo_a = (wm * 64 + (l & 15)) * 32 + (l >> 4) * 8;
  const int fo_b = (wn * 64 + (l & 15)) * 32 + (l >> 4) * 8;

  for (int kt = 0; kt < 13; ++kt) {
    const int kb = kt * 64;
    gload16(gA0 + kb, lA0); gload16(gA0 + kb + (size_t)64 * 832, lA0 + 4096);
    gload16(gA1 + kb, lA1); gload16(gA1 + kb + (size_t)64 * 832, lA1 + 4096);
    gload16(gU  + kb, lU ); gload16(gU  + kb + (size_t)64 * 832, lU  + 4096);
    gload16(gT  + kb, lT ); gload16(gT  + kb + (size_t)64 * 832, lT  + 4096);
    __syncthreads();
    bf16x8 a0[4], a1[4], bu[4], bt[4];
    #pragma unroll
    for (int i = 0; i < 4; ++i) {
      a0[i] = *(const bf16x8*)(As0 + fo_a + i * 16 * 32);
      a1[i] = *(const bf16x8*)(As1 + fo_a + i * 16 * 32);
      bu[i] = *(const bf16x8*)(Bu  + fo_b + i * 16 * 32);
      bt[i] = *(const bf16x8*)(Bt  + fo_b + i * 16 * 32);
    }
    #pragma unroll
    for (int i = 0; i < 4; ++i)
      #pragma unroll
      for (int j = 0; j < 4; ++j) {
        acc0[i][j] = __builtin_amdgcn_mfma_f32_16x16x32_bf16(a0[i], bu[j], acc0[i][j], 0, 0, 0);
        acc1[i][j] = __builtin_amdgcn_mfma_f32_16x16x32_bf16(a1[i], bt[j], acc1[i][j], 0, 0, 0);
      }
    __syncthreads();
  }

  const int r4 = (l >> 4) * 4, cc = l & 15;
  #pragma unroll
  for (int i = 0; i < 4; ++i)
    #pragma unroll
    for (int j = 0; j < 4; ++j) {
      const int col = tn + wn * 64 + j * 16 + cc;
      if (col < K2) {
        #pragma unroll
        for (int r = 0; r < 4; ++r) {
          const int rowg = tm + wm * 64 + i * 16 + r4 + r;
          H[(size_t)rowg * K2 + col] = f2bf(acc0[i][j][r] * acc1[i][j][r]);
        }
      }
    }
}

// ---------- out[16384,2500] = H[.,448] @ G^T : 256x256 tile, 8-phase ----------
#define STAGE(gbase, rowbase, tt, slot)                                            \
  do {                                                                             \
    char* _d = ldsb + (slot) * 16384;                                              \
    gload16((gbase) + (size_t)((rowbase) + sr0) * BSTR + (tt) * 128 + sc0, _d + P0);\
    gload16((gbase) + (size_t)((rowbase) + sr1) * BSTR + (tt) * 128 + sc1, _d + P1);\
  } while (0)

__global__ __launch_bounds__(512, 2) void gemm_big8(const u16* __restrict__ H,
                                                    const u16* __restrict__ G,
                                                    float* __restrict__ out) {
  __shared__ u16 lds[8 * 8192];   // 128 KiB
  char* ldsb = (char*)lds;
  const int tid = threadIdx.x;
  const int lane = tid & 63, wid = tid >> 6;
  const int wm = wid >> 2, wn = wid & 3;

  int bs = (int)blockIdx.x;
  bs = (bs & 7) * 80 + (bs >> 3);                 // XCD swizzle, 640 % 8 == 0
  const int tm = (bs / 10) * 256, tn = (bs % 10) * 256;

  const char* gH = (const char*)H;
  const char* gG = (const char*)G;

  const int P0 = tid * 16, P1 = tid * 16 + 8192;
  const int L0 = P0 ^ (((P0 >> 7) & 7) << 4);
  const int L1 = P1 ^ (((P1 >> 7) & 7) << 4);
  const int sr0 = L0 >> 7, sc0 = L0 & 127;
  const int sr1 = L1 >> 7, sc1 = L1 & 127;

  const int cs0 = ((lane >> 4) * 16) ^ ((lane & 7) << 4);
  const int cs1 = (64 + (lane >> 4) * 16) ^ ((lane & 7) << 4);
  const int arow = (lane & 15) * 128;

  f32x4 acc[8][4] = {};

  STAGE(gH, tm,       0, 0);
  STAGE(gH, tm + 128, 0, 1);
  STAGE(gG, tn,       0, 2);
  STAGE(gG, tn + 128, 0, 3);
  STAGE(gG, tn,       1, 6);
  STAGE(gH, tm,       1, 4);
  VMCNT4();
  BARRIER();

  for (int t = 0; t < 7; ++t) {
    const int cb = t & 1, nb = cb ^ 1;
    const char* bufA = ldsb + (cb * 4 + wm) * 16384;
    const char* bufB = ldsb + (cb * 4 + 2 + (wn >> 1)) * 16384;
    const int boff = (wn & 1) * 8192;
    const int t1 = (t + 1 < 7) ? t + 1 : 6;
    const int t2 = (t + 2 < 7) ? t + 2 : 6;

    bf16x8 a[4][2], b[2][2][2];

    // ---- phase 0 ----
    #pragma unroll
    for (int rf = 0; rf < 4; ++rf) {
      a[rf][0] = *(const bf16x8*)(bufA + rf * 2048 + arow + cs0);
      a[rf][1] = *(const bf16x8*)(bufA + rf * 2048 + arow + cs1);
    }
    #pragma unroll
    for (int cf = 0; cf < 2; ++cf) {
      b[0][cf][0] = *(const bf16x8*)(bufB + boff + cf * 2048 + arow + cs0);
      b[0][cf][1] = *(const bf16x8*)(bufB + boff + cf * 2048 + arow + cs1);
    }
    STAGE(gH, tm + 128, t1, nb * 4 + 1);
    BARRIER();
    __builtin_amdgcn_s_setprio(1);
    #pragma unroll
    for (int rf = 0; rf < 4; ++rf)
      #pragma unroll
      for (int cf = 0; cf < 2; ++cf) {
        acc[rf][cf] = __builtin_amdgcn_mfma_f32_16x16x32_bf16(a[rf][0], b[0][cf][0], acc[rf][cf], 0, 0, 0);
        acc[rf][cf] = __builtin_amdgcn_mfma_f32_16x16x32_bf16(a[rf][1], b[0][cf][1], acc[rf][cf], 0, 0, 0);
      }
    __builtin_amdgcn_s_setprio(0);
    BARRIER();

    // ---- phase 1 ----
    #pragma unroll
    for (int cf = 0; cf < 2; ++cf) {
      b[1][cf][0] = *(const bf16x8*)(bufB + boff + 4096 + cf * 2048 + arow + cs0);
      b[1][cf][1] = *(const bf16x8*)(bufB + boff + 4096 + cf * 2048 + arow + cs1);
    }
    STAGE(gG, tn + 128, t1, nb * 4 + 3);
    BARRIER();
    __builtin_amdgcn_s_setprio(1);
    #pragma unroll
    for (int rf = 0; rf < 4; ++rf)
      #pragma unroll
      for (int cf = 0; cf < 2; ++cf) {
        acc[rf][2 + cf] = __builtin_amdgcn_mfma_f32_16x16x32_bf16(a[rf][0], b[1][cf][0], acc[rf][2 + cf], 0, 0, 0);
        acc[rf][2 + cf] = __builtin_amdgcn_mfma_f32_16x16x32_bf16(a[rf][1], b[1][cf][1], acc[rf][2 + cf], 0, 0, 0);
      }
    __builtin_amdgcn_s_setprio(0);
    BARRIER();

    // ---- phase 2 ----
    #pragma unroll
    for (int rf = 0; rf < 4; ++rf) {
      a[rf][0] = *(const bf16x8*)(bufA + 8192 + rf * 2048 + arow + cs0);
      a[rf][1] = *(const bf16x8*)(bufA + 8192 + rf * 2048 + arow + cs1);
    }
    STAGE(gG, tn, t2, cb * 4 + 2);
    BARRIER();
    __builtin_amdgcn_s_setprio(1);
    #pragma unroll
    for (int rf = 0; rf < 4; ++rf)
      #pragma unroll
      for (int cf = 0; cf < 2; ++cf) {
        acc[4 + rf][cf] = __builtin_amdgcn_mfma_f32_16x16x32_bf16(a[rf][0], b[0][cf][0], acc[4 + rf][cf], 0, 0, 0);
        acc[4 + rf][cf] = __builtin_amdgcn_mfma_f32_16x16x32_bf16(a[rf][1], b[0][cf][1], acc[4 + rf][cf], 0, 0, 0);
      }
    __builtin_amdgcn_s_setprio(0);
    BARRIER();

    // ---- phase 3 ----
    STAGE(gH, tm, t2, cb * 4 + 0);
    BARRIER();
    __builtin_amdgcn_s_setprio(1);
    #pragma unroll
    for (int rf = 0; rf < 4; ++rf)
      #pragma unroll
      for (int cf = 0; cf < 2; ++cf) {
        acc[4 + rf][2 + cf] = __builtin_amdgcn_mfma_f32_16x16x32_bf16(a[rf][0], b[1][cf][0], acc[4 + rf][2 + cf], 0, 0, 0);
        acc[4 + rf][2 + cf] = __builtin_amdgcn_mfma_f32_16x16x32_bf16(a[rf][1], b[1][cf][1], acc[4 + rf][2 + cf], 0, 0, 0);
      }
    __builtin_amdgcn_s_setprio(0);
    VMCNT4();
    BARRIER();
  }

  const int r4 = (lane >> 4) * 4, cc = lane & 15;
  const int rbase = tm + wm * 128 + r4;
  const int cbase = tn + wn * 64 + cc;
  #pragma unroll
  for (int rf = 0; rf < 8; ++rf)
    #pragma unroll
    for (int cf = 0; cf < 4; ++cf) {
      const int col = cbase + cf * 16;
      if (col < NBC) {
        #pragma unroll
        for (int rr = 0; rr < 4; ++rr)
          __builtin_nontemporal_store(acc[rf][cf][rr],
              &out[(size_t)(rbase + rf * 16 + rr) * NBC + col]);
      }
    }
}

extern "C" void kernel_launch(void* const* d_in, const int* in_sizes, int n_in,
                              void* d_out, int out_size, void* d_ws, size_t ws_size,
                              hipStream_t stream) {
  const float* word  = (const float*)d_in[0];
  const float* tag   = (const float*)d_in[1];
  const float* Tm    = (const float*)d_in[2];
  const float* Um    = (const float*)d_in[3];
  const float* Vm    = (const float*)d_in[4];
  const float* Wm    = (const float*)d_in[5];
  const float* first = (const float*)d_in[6];
  float* out = (float*)d_out;
  char* ws = (char*)d_ws;

  u16*   Wbf = (u16*)(ws + OFF_WBF);
  u16*   Ubt = (u16*)(ws + OFF_UBT);
  u16*   Tbt = (u16*)(ws + OFF_TBT);
  u16*   G   = (u16*)(ws + OFF_G);
  u16*   H   = (u16*)(ws + OFF_H);

  hipLaunchKernelGGL(prep_all, dim3(2048), dim3(256), 0, stream,
                     word, first, Um, Tm, tag, Vm, Wm, Wbf, Ubt, Tbt, G);
  hipLaunchKernelGGL(gemm_h,   dim3(128 * 4), dim3(256), 0, stream, Wbf, Ubt, Tbt, H);
  // DIAGNOSTIC: gemm_big8 launched twice (idempotent). dur(R3)-dur(R2)+prep_savings
  // isolates T(gemm_big8) since per-kernel times are invisible under the harness fills.
  hipLaunchKernelGGL(gemm_big8, dim3(640), dim3(512), 0, stream, H, G, out);
  hipLaunchKernelGGL(gemm_big8, dim3(640), dim3(512), 0, stream, H, G, out);
}

// Round 4
// 115.551 us; speedup vs baseline: 2.9379x; 2.9379x over previous
//
#include <hip/hip_runtime.h>

typedef unsigned short u16;
typedef __bf16 bf16x8 __attribute__((ext_vector_type(8)));
typedef float f32x4 __attribute__((ext_vector_type(4)));

#define WEMD 400
#define RANK 396
#define NA   16384     // SEQ*BATCH
#define KP   416       // padded wemd (400->416) for gemm_h K
#define K2   448       // padded rank (396->448) for gemm_big K (7 tiles of 64)
#define BSTR 896       // byte stride of H and G rows (448*2)
#define NBC  2500
#define NBCP 2560

// ---- ws layout (bytes) ----
#define OFF_WBF  0u                 // u16 [16416][416]
#define OFF_UBT  13658112u          // u16 [512][416]
#define OFF_TBT  14084096u          // u16 [512][416]
#define OFF_G    14689280u          // u16 [2560][448]
#define OFF_H    16983040u          // u16 [16384][448]   total ~31.7 MB

__device__ __forceinline__ u16 f2bf(float f) {
  union { float f; unsigned u; } v; v.f = f;
  unsigned u = v.u;
  return (u16)((u + 0x7FFFu + ((u >> 16) & 1u)) >> 16);  // RNE
}

typedef __attribute__((address_space(3))) unsigned char lds_byte;
typedef __attribute__((address_space(1))) const unsigned char glob_byte;

__device__ __forceinline__ void gload16(const void* g, void* l) {
  __builtin_amdgcn_global_load_lds((glob_byte*)g, (lds_byte*)l, 16, 0, 0);
}

// ---------- fused prep: Wbf + Ubt/Tbt + G in one grid-stride kernel ----------
__global__ __launch_bounds__(256) void prep_all(
    const float* __restrict__ word, const float* __restrict__ first,
    const float* __restrict__ U, const float* __restrict__ T,
    const float* __restrict__ tag, const float* __restrict__ V,
    const float* __restrict__ W,
    u16* __restrict__ Wbf, u16* __restrict__ Ubt, u16* __restrict__ Tbt,
    u16* __restrict__ G) {
  const int R0 = 16416 * 104;          // Wbf as float4 items (416/4 = 104 per row)
  const int R1 = 416 << 9;             // U/T transpose: k = j>>9 (0..415), n = j&511
  const int R2 = NBCP * K2;            // G items
  const int total = R0 + R1 + R2;
  for (int i = blockIdx.x * 256 + threadIdx.x; i < total; i += gridDim.x * 256) {
    if (i < R0) {
      int r = i / 104, c4 = i - r * 104;
      ushort4 o = {0, 0, 0, 0};
      if (c4 < 100) {
        const float* src = (r < 32) ? (first + c4 * 4)
                                    : (word + (size_t)(r - 32) * WEMD + c4 * 4);
        float4 v = *(const float4*)src;
        o.x = f2bf(v.x); o.y = f2bf(v.y); o.z = f2bf(v.z); o.w = f2bf(v.w);
      }
      *(ushort4*)(Wbf + (size_t)r * KP + c4 * 4) = o;
    } else if (i < R0 + R1) {
      int j = i - R0;
      int n = j & 511, k = j >> 9;
      u16 uo = 0, to = 0;
      if (n < RANK && k < WEMD) {
        uo = f2bf(U[(size_t)k * RANK + n]);
        to = f2bf(T[(size_t)k * RANK + n]);
      }
      Ubt[(size_t)n * KP + k] = uo;
      Tbt[(size_t)n * KP + k] = to;
    } else {
      int j = i - R0 - R1;
      int bc = j / K2, k = j - bc * K2;
      u16 g = 0;
      if (bc < NBC && k < RANK) {
        int b = bc / 50, c = bc - b * 50;
        float a2 = 0.f, a3 = 0.f;
        #pragma unroll
        for (int e = 0; e < 20; ++e) {
          a2 += tag[b * 20 + e] * V[e * RANK + k];
          a3 += tag[c * 20 + e] * W[e * RANK + k];
        }
        g = f2bf(a2 * a3);
      }
      G[(size_t)bc * K2 + k] = g;
    }
  }
}

// ---------- H = (word@U) * (neighbor@T), bf16 out, stride 448 ----------
__global__ __launch_bounds__(256) void gemm_h(const u16* __restrict__ Wbf,
                                              const u16* __restrict__ Ubt,
                                              const u16* __restrict__ Tbt,
                                              u16* __restrict__ H) {
  __shared__ u16 As0[128 * 32], As1[128 * 32], Bu[128 * 32], Bt[128 * 32];
  const int tid = threadIdx.x;
  const int l = tid & 63, w = tid >> 6;
  const int wm = w >> 1, wn = w & 1;
  const int tm = (blockIdx.x >> 2) * 128, tn = (blockIdx.x & 3) * 128;

  f32x4 acc0[4][4] = {}, acc1[4][4] = {};

  const int srow = tid >> 2;
  const int scolb = (tid & 3) * 16;
  const char* gA0 = (const char*)Wbf + (size_t)(tm + 32 + srow) * 832 + scolb;
  const char* gA1 = (const char*)Wbf + (size_t)(tm + srow) * 832 + scolb;
  const char* gU  = (const char*)Ubt + (size_t)(tn + srow) * 832 + scolb;
  const char* gT  = (const char*)Tbt + (size_t)(tn + srow) * 832 + scolb;
  char* lA0 = (char*)As0 + tid * 16;
  char* lA1 = (char*)As1 + tid * 16;
  char* lU  = (char*)Bu  + tid * 16;
  char* lT  = (char*)Bt  + tid * 16;

  const int fo_a = (wm * 64 + (l & 15)) * 32 + (l >> 4) * 8;
  const int fo_b = (wn * 64 + (l & 15)) * 32 + (l >> 4) * 8;

  for (int kt = 0; kt < 13; ++kt) {
    const int kb = kt * 64;
    gload16(gA0 + kb, lA0); gload16(gA0 + kb + (size_t)64 * 832, lA0 + 4096);
    gload16(gA1 + kb, lA1); gload16(gA1 + kb + (size_t)64 * 832, lA1 + 4096);
    gload16(gU  + kb, lU ); gload16(gU  + kb + (size_t)64 * 832, lU  + 4096);
    gload16(gT  + kb, lT ); gload16(gT  + kb + (size_t)64 * 832, lT  + 4096);
    __syncthreads();
    bf16x8 a0[4], a1[4], bu[4], bt[4];
    #pragma unroll
    for (int i = 0; i < 4; ++i) {
      a0[i] = *(const bf16x8*)(As0 + fo_a + i * 16 * 32);
      a1[i] = *(const bf16x8*)(As1 + fo_a + i * 16 * 32);
      bu[i] = *(const bf16x8*)(Bu  + fo_b + i * 16 * 32);
      bt[i] = *(const bf16x8*)(Bt  + fo_b + i * 16 * 32);
    }
    #pragma unroll
    for (int i = 0; i < 4; ++i)
      #pragma unroll
      for (int j = 0; j < 4; ++j) {
        acc0[i][j] = __builtin_amdgcn_mfma_f32_16x16x32_bf16(a0[i], bu[j], acc0[i][j], 0, 0, 0);
        acc1[i][j] = __builtin_amdgcn_mfma_f32_16x16x32_bf16(a1[i], bt[j], acc1[i][j], 0, 0, 0);
      }
    __syncthreads();
  }

  const int r4 = (l >> 4) * 4, cc = l & 15;
  #pragma unroll
  for (int i = 0; i < 4; ++i)
    #pragma unroll
    for (int j = 0; j < 4; ++j) {
      const int col = tn + wn * 64 + j * 16 + cc;
      if (col < K2) {
        #pragma unroll
        for (int r = 0; r < 4; ++r) {
          const int rowg = tm + wm * 64 + i * 16 + r4 + r;
          H[(size_t)rowg * K2 + col] = f2bf(acc0[i][j][r] * acc1[i][j][r]);
        }
      }
    }
}

// ---------- out[16384,2500] = H[.,448] @ G^T ----------
// m97 structure: 128x128 tile, BK=64, 256 thr (4 waves 2x2), single-buffered
// 32 KiB LDS -> 3 blocks/CU co-residency provides the pipeline overlap
// (epilogue writes / barrier drains of one block overlap MFMA of another).
// LDS slots [128 rows][128 B] with the validated st-swizzle:
//   physical = logical ^ ((row&7)<<4), both on stage (inverse-swizzled
//   global source, linear LDS dest) and on read.
__global__ __launch_bounds__(256, 3) void gemm_big2(const u16* __restrict__ H,
                                                    const u16* __restrict__ G,
                                                    float* __restrict__ out) {
  __shared__ u16 lds[2 * 8192];   // A 16 KiB + B 16 KiB
  char* ldsb = (char*)lds;
  const int tid = threadIdx.x;
  const int lane = tid & 63, wid = tid >> 6;
  const int wm = wid >> 1, wn = wid & 1;

  int bs = (int)blockIdx.x;
  bs = (bs & 7) * 320 + (bs >> 3);              // XCD swizzle, 2560 % 8 == 0
  const int tm = (bs / 20) * 128, tn = (bs % 20) * 128;

  const char* gH = (const char*)H + (size_t)tm * BSTR;
  const char* gG = (const char*)G + (size_t)tn * BSTR;

  // stage addressing: 4 x 16B per thread per operand tile
  int sP[4], sR[4], sC[4];
  #pragma unroll
  for (int q = 0; q < 4; ++q) {
    int P = tid * 16 + q * 4096;
    int L = P ^ (((P >> 7) & 7) << 4);
    sP[q] = P; sR[q] = L >> 7; sC[q] = L & 127;
  }
  const int arow = (lane & 15) * 128;
  const int sw = (lane & 7) << 4;

  f32x4 acc[4][4] = {};

  for (int kt = 0; kt < 7; ++kt) {
    const int kb = kt * 128;                    // byte offset in K
    #pragma unroll
    for (int q = 0; q < 4; ++q) {
      gload16(gH + (size_t)sR[q] * BSTR + kb + sC[q], ldsb + sP[q]);
      gload16(gG + (size_t)sR[q] * BSTR + kb + sC[q], ldsb + 16384 + sP[q]);
    }
    __syncthreads();                            // drains vmcnt (compiler-inserted)
    #pragma unroll
    for (int ks = 0; ks < 2; ++ks) {
      const int csw = (ks * 64 + (lane >> 4) * 16) ^ sw;
      bf16x8 a[4], b[4];
      #pragma unroll
      for (int rf = 0; rf < 4; ++rf)
        a[rf] = *(const bf16x8*)(ldsb + wm * 8192 + rf * 2048 + arow + csw);
      #pragma unroll
      for (int cf = 0; cf < 4; ++cf)
        b[cf] = *(const bf16x8*)(ldsb + 16384 + wn * 8192 + cf * 2048 + arow + csw);
      #pragma unroll
      for (int rf = 0; rf < 4; ++rf)
        #pragma unroll
        for (int cf = 0; cf < 4; ++cf)
          acc[rf][cf] = __builtin_amdgcn_mfma_f32_16x16x32_bf16(a[rf], b[cf], acc[rf][cf], 0, 0, 0);
    }
    __syncthreads();                            // protect LDS before next stage
  }

  const int r4 = (lane >> 4) * 4, cc = lane & 15;
  const int rbase = tm + wm * 64 + r4;
  const int cbase = tn + wn * 64 + cc;
  #pragma unroll
  for (int rf = 0; rf < 4; ++rf)
    #pragma unroll
    for (int cf = 0; cf < 4; ++cf) {
      const int col = cbase + cf * 16;
      if (col < NBC) {
        #pragma unroll
        for (int rr = 0; rr < 4; ++rr)
          out[(size_t)(rbase + rf * 16 + rr) * NBC + col] = acc[rf][cf][rr];
      }
    }
}

extern "C" void kernel_launch(void* const* d_in, const int* in_sizes, int n_in,
                              void* d_out, int out_size, void* d_ws, size_t ws_size,
                              hipStream_t stream) {
  const float* word  = (const float*)d_in[0];
  const float* tag   = (const float*)d_in[1];
  const float* Tm    = (const float*)d_in[2];
  const float* Um    = (const float*)d_in[3];
  const float* Vm    = (const float*)d_in[4];
  const float* Wm    = (const float*)d_in[5];
  const float* first = (const float*)d_in[6];
  float* out = (float*)d_out;
  char* ws = (char*)d_ws;

  u16*   Wbf = (u16*)(ws + OFF_WBF);
  u16*   Ubt = (u16*)(ws + OFF_UBT);
  u16*   Tbt = (u16*)(ws + OFF_TBT);
  u16*   G   = (u16*)(ws + OFF_G);
  u16*   H   = (u16*)(ws + OFF_H);

  hipLaunchKernelGGL(prep_all, dim3(2048), dim3(256), 0, stream,
                     word, first, Um, Tm, tag, Vm, Wm, Wbf, Ubt, Tbt, G);
  hipLaunchKernelGGL(gemm_h,   dim3(128 * 4), dim3(256), 0, stream, Wbf, Ubt, Tbt, H);
  hipLaunchKernelGGL(gemm_big2, dim3(2560), dim3(256), 0, stream, H, G, out);
}